// Round 13
// baseline (14158.228 us; speedup 1.0000x reference)
//
#include <hip/hip_runtime.h>
#include <hip/hip_bf16.h>

typedef __attribute__((ext_vector_type(4))) float f4;
typedef __attribute__((ext_vector_type(4))) float f32x4;
typedef __attribute__((ext_vector_type(8))) short bf16x8;
typedef __attribute__((ext_vector_type(4))) unsigned u32x4;
typedef unsigned long long ull;

// ---------------- workspace layout (bytes) ----------------
#define OFF_XCAT   0ull                 // ushort [1024][128][512]  time-major LSTM input
#define OFF_WCAT   134217728ull         // ushort [2048][1024]      packed LSTM weights
#define OFF_BIAS   138412032ull         // float  [2048]
#define OFF_HW     138420224ull         // uint   [2][8][16][512]   tagged h words: (h_bf16<<16)|step_tag
#define OFF_CTR    138944512ull         // uint   [256]             counters/diag
#define WS_NEED    138945536ull

__device__ inline unsigned short f2bf(float x){
  unsigned u = __float_as_uint(x);
  unsigned r = (u + 0x7FFFu + ((u >> 16) & 1u)) >> 16;   // RNE
  return (unsigned short)r;
}
__device__ inline float bf2f(unsigned short s){ return __uint_as_float(((unsigned)s) << 16); }

// ---------------- diagnostic fill (absmax is the debug channel) ----------------
__global__ void __launch_bounds__(256) diag_write(float* out, float val){
  out[blockIdx.x * 256 + threadIdx.x] = val;
}

// ---------------- weight repack ----------------
__global__ void __launch_bounds__(256) prep_w(
    const float* Wii, const float* Wif, const float* Wig, const float* Wio,
    const float* Whi, const float* Whf, const float* Whg, const float* Who,
    const float* Bii, const float* Bif, const float* Big, const float* Bio,
    const float* Bhi, const float* Bhf, const float* Bhg, const float* Bho,
    unsigned short* Wcat, float* bias_cat){
  int e = blockIdx.x * 256 + threadIdx.x;        // < 2048*1024
  int col = e >> 10, k = e & 1023;
  int u = col >> 2, g = col & 3;
  float v;
  if (k < 512){
    const float* p = (g==0)?Wii:((g==1)?Wif:((g==2)?Wig:Wio));
    v = p[u*512 + k];
  } else {
    const float* p = (g==0)?Whi:((g==1)?Whf:((g==2)?Whg:Who));
    v = p[u*512 + (k-512)];
  }
  Wcat[e] = f2bf(v);
  if (e < 2048){
    int u2 = e >> 2, g2 = e & 3;
    const float* bx = (g2==0)?Bii:((g2==1)?Bif:((g2==2)?Big:Bio));
    const float* bh = (g2==0)?Bhi:((g2==1)?Bhf:((g2==2)?Bhg:Bho));
    bias_cat[e] = bx[u2] + bh[u2];
  }
}

// ---------------- fused stage A (proven r2/r3) ----------------
__global__ void __launch_bounds__(256) stageA_fused(
    const float* __restrict__ xnum, const int* __restrict__ xstate,
    const float* __restrict__ emb,
    const float* __restrict__ num_w0, const float* __restrict__ num_b0,
    const float* __restrict__ num_w1, const float* __restrict__ num_b1,
    const float* __restrict__ st_w0,  const float* __restrict__ st_b0,
    const float* __restrict__ st_w1,  const float* __restrict__ st_b1,
    unsigned short* __restrict__ Xcat){
  __shared__ float Wt[32*256];
  __shared__ float xb[16*68];
  __shared__ float h1[16*260];
  int tid = threadIdx.x;
  long tok0 = (long)blockIdx.x * 16;
  int tg = tid >> 6, c4 = tid & 63;

  #pragma unroll 1
  for (int br = 0; br < 2; ++br){
    const float* W0 = br ? st_w0 : num_w0;
    const float* b0 = br ? st_b0 : num_b0;
    const float* W1 = br ? st_w1 : num_w1;
    const float* b1 = br ? st_b1 : num_b1;

    __syncthreads();
    if (br == 0){
      int tk = tid >> 4, q = tid & 15;
      f4 v = *(const f4*)(xnum + (tok0+tk)*64 + q*4);
      float* d = xb + tk*68 + q*4;
      d[0]=v.x; d[1]=v.y; d[2]=v.z; d[3]=v.w;
    } else {
      int tk = tid >> 4, j = tid & 15;
      int idx = xstate[(tok0+tk)*16 + j];
      f4 v = *(const f4*)(emb + idx*4);
      float* d = xb + tk*68 + j*4;
      d[0]=v.x; d[1]=v.y; d[2]=v.z; d[3]=v.w;
    }

    float acc[4][4];
    { f4 bv = *(const f4*)(b0 + c4*4);
      #pragma unroll
      for (int j=0;j<4;j++){ acc[j][0]=bv.x; acc[j][1]=bv.y; acc[j][2]=bv.z; acc[j][3]=bv.w; } }
    for (int kh=0; kh<2; ++kh){
      __syncthreads();
      { int c = tid;
        const f4* src = (const f4*)(W0 + c*64 + kh*32);
        #pragma unroll
        for (int q=0;q<8;q++){
          f4 v = src[q];
          Wt[(q*4+0)*256 + c] = v.x; Wt[(q*4+1)*256 + c] = v.y;
          Wt[(q*4+2)*256 + c] = v.z; Wt[(q*4+3)*256 + c] = v.w;
        }
      }
      __syncthreads();
      for (int kq=0; kq<8; kq++){
        int k0 = kh*32 + kq*4;
        f4 a0 = *(const f4*)(xb + (tg*4+0)*68 + k0);
        f4 a1 = *(const f4*)(xb + (tg*4+1)*68 + k0);
        f4 a2 = *(const f4*)(xb + (tg*4+2)*68 + k0);
        f4 a3 = *(const f4*)(xb + (tg*4+3)*68 + k0);
        f4 w0 = *(const f4*)(Wt + (kq*4+0)*256 + c4*4);
        f4 w1 = *(const f4*)(Wt + (kq*4+1)*256 + c4*4);
        f4 w2 = *(const f4*)(Wt + (kq*4+2)*256 + c4*4);
        f4 w3 = *(const f4*)(Wt + (kq*4+3)*256 + c4*4);
        #pragma unroll
        for (int j=0;j<4;j++){
          f4 a = (j==0)?a0:((j==1)?a1:((j==2)?a2:a3));
          #pragma unroll
          for (int d=0; d<4; d++)
            acc[j][d] += a.x*w0[d] + a.y*w1[d] + a.z*w2[d] + a.w*w3[d];
        }
      }
    }
    #pragma unroll
    for (int j=0;j<4;j++){
      float v0=fmaxf(acc[j][0],0.f), v1=fmaxf(acc[j][1],0.f);
      float v2=fmaxf(acc[j][2],0.f), v3=fmaxf(acc[j][3],0.f);
      float s1 = v0+v1+v2+v3, s2 = v0*v0+v1*v1+v2*v2+v3*v3;
      for (int off=1; off<64; off<<=1){ s1 += __shfl_xor(s1, off); s2 += __shfl_xor(s2, off); }
      float mu = s1 * (1.f/256.f);
      float rs = rsqrtf(s2*(1.f/256.f) - mu*mu + 1e-5f);
      f4 o; o.x=(v0-mu)*rs; o.y=(v1-mu)*rs; o.z=(v2-mu)*rs; o.w=(v3-mu)*rs;
      *(f4*)(h1 + (tg*4+j)*260 + c4*4) = o;
    }

    float ac2[4][4];
    { f4 bv = *(const f4*)(b1 + c4*4);
      #pragma unroll
      for (int j=0;j<4;j++){ ac2[j][0]=bv.x; ac2[j][1]=bv.y; ac2[j][2]=bv.z; ac2[j][3]=bv.w; } }
    for (int kh=0; kh<8; ++kh){
      __syncthreads();
      { int c = tid;
        const f4* src = (const f4*)(W1 + c*256 + kh*32);
        #pragma unroll
        for (int q=0;q<8;q++){
          f4 v = src[q];
          Wt[(q*4+0)*256 + c] = v.x; Wt[(q*4+1)*256 + c] = v.y;
          Wt[(q*4+2)*256 + c] = v.z; Wt[(q*4+3)*256 + c] = v.w;
        }
      }
      __syncthreads();
      for (int kq=0; kq<8; kq++){
        int k0 = kh*32 + kq*4;
        f4 a0 = *(const f4*)(h1 + (tg*4+0)*260 + k0);
        f4 a1 = *(const f4*)(h1 + (tg*4+1)*260 + k0);
        f4 a2 = *(const f4*)(h1 + (tg*4+2)*260 + k0);
        f4 a3 = *(const f4*)(h1 + (tg*4+3)*260 + k0);
        f4 w0 = *(const f4*)(Wt + (kq*4+0)*256 + c4*4);
        f4 w1 = *(const f4*)(Wt + (kq*4+1)*256 + c4*4);
        f4 w2 = *(const f4*)(Wt + (kq*4+2)*256 + c4*4);
        f4 w3 = *(const f4*)(Wt + (kq*4+3)*256 + c4*4);
        #pragma unroll
        for (int j=0;j<4;j++){
          f4 a = (j==0)?a0:((j==1)?a1:((j==2)?a2:a3));
          #pragma unroll
          for (int d=0; d<4; d++)
            ac2[j][d] += a.x*w0[d] + a.y*w1[d] + a.z*w2[d] + a.w*w3[d];
        }
      }
    }
    #pragma unroll
    for (int j=0;j<4;j++){
      float v0=fmaxf(ac2[j][0],0.f), v1=fmaxf(ac2[j][1],0.f);
      float v2=fmaxf(ac2[j][2],0.f), v3=fmaxf(ac2[j][3],0.f);
      float s1 = v0+v1+v2+v3, s2 = v0*v0+v1*v1+v2*v2+v3*v3;
      for (int off=1; off<64; off<<=1){ s1 += __shfl_xor(s1, off); s2 += __shfl_xor(s2, off); }
      float mu = s1 * (1.f/256.f);
      float rs = rsqrtf(s2*(1.f/256.f) - mu*mu + 1e-5f);
      long tok = tok0 + tg*4 + j;
      long bb = tok >> 10, ss = tok & 1023;
      unsigned short* o = Xcat + (ss*128 + bb)*512 + br*256 + c4*4;
      unsigned lo = (unsigned)f2bf((v0-mu)*rs) | ((unsigned)f2bf((v1-mu)*rs) << 16);
      unsigned hi = (unsigned)f2bf((v2-mu)*rs) | ((unsigned)f2bf((v3-mu)*rs) << 16);
      ((unsigned*)o)[0] = lo; ((unsigned*)o)[1] = hi;
    }
  }
}

// ---------------- persistent LSTM kernel (fragment-direct tagged exchange, no LDS, no barrier) ----------------
// grid = 256 WGs x 256 thr. group g = blockIdx&7 (16 batch rows), member m = blockIdx>>3.
// h word = (h_bf16<<16)|step_tag. For h-chunk s, lane needs exactly 8 contiguous words
// (units 32s+8*(lane>>4)..+7 of row lane&15) = 2 dwordx4 loads. Poll until 8 tags==t,
// bit-pack hi16 -> bf16x8, MFMA. No LDS tile, no __syncthreads in the loop: waves are
// autonomous; ready chunks are consumed while stragglers' stores are in flight.
// 2-parity safety: wave publishes t+1 only after consuming all parity-(t&1) fragments.
__global__ void __launch_bounds__(256, 1) lstm_pk(
    const unsigned short* __restrict__ Xcat,
    const unsigned short* __restrict__ Wcat,
    const float* __restrict__ bias_cat,
    unsigned int* __restrict__ hw,
    unsigned int* __restrict__ ctr){
  __shared__ int okf, sdead;
  int tid = threadIdx.x;
  int lane = tid & 63, w = tid >> 6;
  int g = blockIdx.x & 7, m = blockIdx.x >> 3;

  // stationary weights: cols 64m+16w+(lane&15), k = s*32+(lane>>4)*8
  int colg = 64*m + 16*w + (lane & 15);
  bf16x8 wf[32];
  {
    const bf16x8* wsrc = (const bf16x8*)(Wcat + (long)colg*1024 + (lane>>4)*8);
    #pragma unroll
    for (int s=0;s<32;s++) wf[s] = wsrc[s*4];
  }
  int cb = 64*m + 16*w + 4*(lane>>4);
  f32x4 bias4;
  bias4.x = bias_cat[cb+0]; bias4.y = bias_cat[cb+1];
  bias4.z = bias_cat[cb+2]; bias4.w = bias_cat[cb+3];

  // co-residency check (bounded; no hang)
  if (tid == 0){
    __hip_atomic_fetch_add(&ctr[255], 1u, __ATOMIC_RELAXED, __HIP_MEMORY_SCOPE_AGENT);
    unsigned v = 0; int it = 0;
    do {
      v = __hip_atomic_load(&ctr[255], __ATOMIC_RELAXED, __HIP_MEMORY_SCOPE_AGENT);
      if (v >= 256u) break;
      __builtin_amdgcn_s_sleep(8);
    } while (++it < 2000000);
    okf = (v >= 256u) ? 1 : 0;
    sdead = 0;
  }
  __syncthreads();
  if (!okf) return;

  float cst = 0.f;

  // prologue: x-part for t=0
  f32x4 acc0, acc1;
  {
    bf16x8 xf[16];
    const bf16x8* xsrc = (const bf16x8*)(Xcat + ((long)0*128 + g*16 + (lane&15))*512 + (lane>>4)*8);
    #pragma unroll
    for (int s=0;s<16;s++) xf[s] = xsrc[s*4];
    acc0 = bias4;
    acc1.x=0.f; acc1.y=0.f; acc1.z=0.f; acc1.w=0.f;
    #pragma unroll
    for (int s=0;s<16;s+=2){
      acc0 = __builtin_amdgcn_mfma_f32_16x16x32_bf16(wf[s],   xf[s],   acc0, 0, 0, 0);
      acc1 = __builtin_amdgcn_mfma_f32_16x16x32_bf16(wf[s+1], xf[s+1], acc1, 0, 0, 0);
    }
  }

  // per-lane fragment base: row = lane&15, k-slot = (lane>>4)*8
  int bad_t = -1;

  #pragma unroll 1
  for (int t=0; t<1024; ++t){
    unsigned tt = (unsigned)t & 0xFFFFu;    // memset'd tag 0 == t at t=0 (h_0 = 0)
    const unsigned* hbase = hw + ((long)(t&1)*65536) + g*8192 + (lane&15)*512 + (lane>>4)*8;
    // ---- h-part: 16 fragment-direct chunks ----
    #pragma unroll 4
    for (int s=0;s<16;s++){
      u32x4 v0, v1;
      int itc = 0;
      const unsigned* p = hbase + 32*s;
      for (;;){
        asm volatile(
          "global_load_dwordx4 %0, %2, off sc1\n\t"
          "global_load_dwordx4 %1, %2, off offset:16 sc1\n\t"
          "s_waitcnt vmcnt(0)"
          : "=&v"(v0), "=&v"(v1) : "v"(p) : "memory");
        unsigned bad = ((v0.x^tt)|(v0.y^tt)|(v0.z^tt)|(v0.w^tt)
                       |(v1.x^tt)|(v1.y^tt)|(v1.z^tt)|(v1.w^tt)) & 0xFFFFu;
        if (!bad) break;
        if (++itc > 300000){ bad_t = t; break; }
        if ((itc & 255) == 255 && *(volatile int*)&sdead) { bad_t = t; break; }
      }
      if (bad_t >= 0) break;
      union { unsigned u[4]; bf16x8 b; } cv;
      cv.u[0] = (v0.x >> 16) | (v0.y & 0xFFFF0000u);
      cv.u[1] = (v0.z >> 16) | (v0.w & 0xFFFF0000u);
      cv.u[2] = (v1.x >> 16) | (v1.y & 0xFFFF0000u);
      cv.u[3] = (v1.z >> 16) | (v1.w & 0xFFFF0000u);
      if (s & 1) acc1 = __builtin_amdgcn_mfma_f32_16x16x32_bf16(wf[16+s], cv.b, acc1, 0, 0, 0);
      else       acc0 = __builtin_amdgcn_mfma_f32_16x16x32_bf16(wf[16+s], cv.b, acc0, 0, 0, 0);
    }
    if (bad_t >= 0){
      *(volatile int*)&sdead = 1;
      __hip_atomic_store(&ctr[252], (unsigned)(bad_t+1), __ATOMIC_RELAXED, __HIP_MEMORY_SCOPE_AGENT);
      break;
    }
    // ---- gates & state update ----
    float gi = acc0.x + acc1.x, gf = acc0.y + acc1.y;
    float gg = acc0.z + acc1.z, go = acc0.w + acc1.w;
    float iv = 1.f / (1.f + __expf(-gi));
    float fv = 1.f / (1.f + __expf(-gf));
    float e2 = __expf(-2.f * gg);
    float gv = (1.f - e2) / (1.f + e2);
    float ov = 1.f / (1.f + __expf(-go));
    cst = fv * cst + iv * gv;
    float e2c = __expf(-2.f * cst);
    float hout = ov * (1.f - e2c) / (1.f + e2c);
    // ---- publish h_{t+1} as tagged word (fire-and-forget, ASAP) ----
    {
      unsigned short hb16 = f2bf(hout);
      int unit = 16*m + 4*w + (lane >> 4);
      int row  = lane & 15;
      unsigned word = ((unsigned)hb16 << 16) | (unsigned)((t+1) & 0xFFFF);
      unsigned int* dst = hw + ((long)((t+1)&1)*65536) + g*8192 + row*512 + unit;
      __hip_atomic_store(dst, word, __ATOMIC_RELAXED, __HIP_MEMORY_SCOPE_AGENT);
    }
    // ---- x-part for t+1 (overlaps store visibility across the group) ----
    {
      int tn = (t < 1023) ? (t+1) : 1023;
      bf16x8 xf[16];
      const bf16x8* xsrc = (const bf16x8*)(Xcat + ((long)tn*128 + g*16 + (lane&15))*512 + (lane>>4)*8);
      #pragma unroll
      for (int s=0;s<16;s++) xf[s] = xsrc[s*4];
      acc0 = bias4;
      acc1.x=0.f; acc1.y=0.f; acc1.z=0.f; acc1.w=0.f;
      #pragma unroll
      for (int s=0;s<16;s+=2){
        acc0 = __builtin_amdgcn_mfma_f32_16x16x32_bf16(wf[s],   xf[s],   acc0, 0, 0, 0);
        acc1 = __builtin_amdgcn_mfma_f32_16x16x32_bf16(wf[s+1], xf[s+1], acc1, 0, 0, 0);
      }
    }
  }

  __syncthreads();
  if (tid == 0 && !sdead)
    __hip_atomic_fetch_add(&ctr[251], 1u, __ATOMIC_RELAXED, __HIP_MEMORY_SCOPE_AGENT);
}

// ---------------- output projection (reads tagged words, parity 0) ----------------
__global__ void __launch_bounds__(256) out_gemm(
    const unsigned int* __restrict__ hw, const unsigned int* __restrict__ ctr,
    const float* __restrict__ out_w, const float* __restrict__ out_b,
    float* __restrict__ out){
  unsigned done = ctr[251], arriv = ctr[255], dead = ctr[252];
  if (dead != 0u || done != 256u){
    float v = dead ? (20000.f + (float)dead) : (10000.f + (float)arriv);
    if (threadIdx.x < 32) out[blockIdx.x*32 + threadIdx.x] = v;
    return;
  }
  __shared__ float part[8][32];
  int b = blockIdx.x;
  int g = b >> 4, r = b & 15;
  const unsigned int* hrow = hw + (long)g*8192 + r*512;   // parity 0 holds h after step 1024
  int col = threadIdx.x & 31, p = threadIdx.x >> 5;
  float s = 0.f;
  for (int u = p*64; u < p*64 + 64; ++u)
    s += bf2f((unsigned short)(hrow[u] >> 16)) * out_w[col*512 + u];
  part[p][col] = s;
  __syncthreads();
  if (p == 0){
    float t = out_b[col];
    #pragma unroll
    for (int i=0;i<8;i++) t += part[i][col];
    out[b*32 + col] = t;
  }
}

extern "C" void kernel_launch(void* const* d_in, const int* in_sizes, int n_in,
                              void* d_out, int out_size, void* d_ws, size_t ws_size,
                              hipStream_t stream){
  const float* x_num   = (const float*)d_in[0];
  const int*   x_state = (const int*)d_in[1];
  const float* num_w0  = (const float*)d_in[2];
  const float* num_b0  = (const float*)d_in[3];
  const float* num_w1  = (const float*)d_in[4];
  const float* num_b1  = (const float*)d_in[5];
  const float* emb     = (const float*)d_in[6];
  const float* st_w0   = (const float*)d_in[7];
  const float* st_b0   = (const float*)d_in[8];
  const float* st_w1   = (const float*)d_in[9];
  const float* st_b1   = (const float*)d_in[10];
  const float* Wii = (const float*)d_in[11];
  const float* Whi = (const float*)d_in[12];
  const float* Wif = (const float*)d_in[13];
  const float* Whf = (const float*)d_in[14];
  const float* Wig = (const float*)d_in[15];
  const float* Whg = (const float*)d_in[16];
  const float* Wio = (const float*)d_in[17];
  const float* Who = (const float*)d_in[18];
  const float* Bii = (const float*)d_in[19];
  const float* Bhi = (const float*)d_in[20];
  const float* Bif = (const float*)d_in[21];
  const float* Bhf = (const float*)d_in[22];
  const float* Big = (const float*)d_in[23];
  const float* Bhg = (const float*)d_in[24];
  const float* Bio = (const float*)d_in[25];
  const float* Bho = (const float*)d_in[26];
  const float* out_w = (const float*)d_in[27];
  const float* out_b = (const float*)d_in[28];

  float* out = (float*)d_out;

  // sentinel: if later launches silently fail, absmax ~= 50000
  diag_write<<<16, 256, 0, stream>>>(out, 50000.f);

  if (ws_size < WS_NEED){
    diag_write<<<16, 256, 0, stream>>>(out, 100000.f + (float)(ws_size >> 20));
    return;
  }

  char* ws = (char*)d_ws;
  unsigned short* Xcat = (unsigned short*)(ws + OFF_XCAT);
  unsigned short* Wcat = (unsigned short*)(ws + OFF_WCAT);
  float* bias_cat      = (float*)(ws + OFF_BIAS);
  unsigned int* hw     = (unsigned int*)(ws + OFF_HW);
  unsigned int* ctr    = (unsigned int*)(ws + OFF_CTR);

  // zero tagged-word h buffer + counters every call (tags restart; h_0 = 0 with tag 0)
  hipMemsetAsync(ws + OFF_HW, 0, 524288 + 1024, stream);

  prep_w<<<8192, 256, 0, stream>>>(Wii, Wif, Wig, Wio, Whi, Whf, Whg, Who,
                                   Bii, Bif, Big, Bio, Bhi, Bhf, Bhg, Bho,
                                   Wcat, bias_cat);

  stageA_fused<<<8192, 256, 0, stream>>>(x_num, x_state, emb,
                                         num_w0, num_b0, num_w1, num_b1,
                                         st_w0, st_b0, st_w1, st_b1, Xcat);

  lstm_pk<<<256, 256, 0, stream>>>(Xcat, Wcat, bias_cat, hw, ctr);

  out_gemm<<<128, 256, 0, stream>>>(hw, ctr, out_w, out_b, out);
}

// Round 14
// 6920.081 us; speedup vs baseline: 2.0460x; 2.0460x over previous
//
#include <hip/hip_runtime.h>
#include <hip/hip_bf16.h>

typedef __attribute__((ext_vector_type(4))) float f4;
typedef __attribute__((ext_vector_type(4))) float f32x4;
typedef __attribute__((ext_vector_type(8))) short bf16x8;
typedef __attribute__((ext_vector_type(4))) unsigned u32x4;
typedef unsigned long long ull;

// ---------------- workspace layout (bytes) ----------------
#define OFF_XCAT   0ull                 // ushort [1024][128][512]  time-major LSTM input
#define OFF_WCAT   134217728ull         // ushort [2048][1024]      packed LSTM weights
#define OFF_BIAS   138412032ull         // float  [2048]
#define OFF_HW     138420224ull         // uint   [2][8][16][512]   tagged h words: (h_bf16<<16)|step_tag
#define OFF_CTR    138944512ull         // uint   [256]             counters/diag
#define WS_NEED    138945536ull

__device__ inline unsigned short f2bf(float x){
  unsigned u = __float_as_uint(x);
  unsigned r = (u + 0x7FFFu + ((u >> 16) & 1u)) >> 16;   // RNE
  return (unsigned short)r;
}
__device__ inline float bf2f(unsigned short s){ return __uint_as_float(((unsigned)s) << 16); }

// ---------------- diagnostic fill (absmax is the debug channel) ----------------
__global__ void __launch_bounds__(256) diag_write(float* out, float val){
  out[blockIdx.x * 256 + threadIdx.x] = val;
}

// ---------------- weight repack ----------------
__global__ void __launch_bounds__(256) prep_w(
    const float* Wii, const float* Wif, const float* Wig, const float* Wio,
    const float* Whi, const float* Whf, const float* Whg, const float* Who,
    const float* Bii, const float* Bif, const float* Big, const float* Bio,
    const float* Bhi, const float* Bhf, const float* Bhg, const float* Bho,
    unsigned short* Wcat, float* bias_cat){
  int e = blockIdx.x * 256 + threadIdx.x;        // < 2048*1024
  int col = e >> 10, k = e & 1023;
  int u = col >> 2, g = col & 3;
  float v;
  if (k < 512){
    const float* p = (g==0)?Wii:((g==1)?Wif:((g==2)?Wig:Wio));
    v = p[u*512 + k];
  } else {
    const float* p = (g==0)?Whi:((g==1)?Whf:((g==2)?Whg:Who));
    v = p[u*512 + (k-512)];
  }
  Wcat[e] = f2bf(v);
  if (e < 2048){
    int u2 = e >> 2, g2 = e & 3;
    const float* bx = (g2==0)?Bii:((g2==1)?Bif:((g2==2)?Big:Bio));
    const float* bh = (g2==0)?Bhi:((g2==1)?Bhf:((g2==2)?Bhg:Bho));
    bias_cat[e] = bx[u2] + bh[u2];
  }
}

// ---------------- fused stage A (proven r2/r3) ----------------
__global__ void __launch_bounds__(256) stageA_fused(
    const float* __restrict__ xnum, const int* __restrict__ xstate,
    const float* __restrict__ emb,
    const float* __restrict__ num_w0, const float* __restrict__ num_b0,
    const float* __restrict__ num_w1, const float* __restrict__ num_b1,
    const float* __restrict__ st_w0,  const float* __restrict__ st_b0,
    const float* __restrict__ st_w1,  const float* __restrict__ st_b1,
    unsigned short* __restrict__ Xcat){
  __shared__ float Wt[32*256];
  __shared__ float xb[16*68];
  __shared__ float h1[16*260];
  int tid = threadIdx.x;
  long tok0 = (long)blockIdx.x * 16;
  int tg = tid >> 6, c4 = tid & 63;

  #pragma unroll 1
  for (int br = 0; br < 2; ++br){
    const float* W0 = br ? st_w0 : num_w0;
    const float* b0 = br ? st_b0 : num_b0;
    const float* W1 = br ? st_w1 : num_w1;
    const float* b1 = br ? st_b1 : num_b1;

    __syncthreads();
    if (br == 0){
      int tk = tid >> 4, q = tid & 15;
      f4 v = *(const f4*)(xnum + (tok0+tk)*64 + q*4);
      float* d = xb + tk*68 + q*4;
      d[0]=v.x; d[1]=v.y; d[2]=v.z; d[3]=v.w;
    } else {
      int tk = tid >> 4, j = tid & 15;
      int idx = xstate[(tok0+tk)*16 + j];
      f4 v = *(const f4*)(emb + idx*4);
      float* d = xb + tk*68 + j*4;
      d[0]=v.x; d[1]=v.y; d[2]=v.z; d[3]=v.w;
    }

    float acc[4][4];
    { f4 bv = *(const f4*)(b0 + c4*4);
      #pragma unroll
      for (int j=0;j<4;j++){ acc[j][0]=bv.x; acc[j][1]=bv.y; acc[j][2]=bv.z; acc[j][3]=bv.w; } }
    for (int kh=0; kh<2; ++kh){
      __syncthreads();
      { int c = tid;
        const f4* src = (const f4*)(W0 + c*64 + kh*32);
        #pragma unroll
        for (int q=0;q<8;q++){
          f4 v = src[q];
          Wt[(q*4+0)*256 + c] = v.x; Wt[(q*4+1)*256 + c] = v.y;
          Wt[(q*4+2)*256 + c] = v.z; Wt[(q*4+3)*256 + c] = v.w;
        }
      }
      __syncthreads();
      for (int kq=0; kq<8; kq++){
        int k0 = kh*32 + kq*4;
        f4 a0 = *(const f4*)(xb + (tg*4+0)*68 + k0);
        f4 a1 = *(const f4*)(xb + (tg*4+1)*68 + k0);
        f4 a2 = *(const f4*)(xb + (tg*4+2)*68 + k0);
        f4 a3 = *(const f4*)(xb + (tg*4+3)*68 + k0);
        f4 w0 = *(const f4*)(Wt + (kq*4+0)*256 + c4*4);
        f4 w1 = *(const f4*)(Wt + (kq*4+1)*256 + c4*4);
        f4 w2 = *(const f4*)(Wt + (kq*4+2)*256 + c4*4);
        f4 w3 = *(const f4*)(Wt + (kq*4+3)*256 + c4*4);
        #pragma unroll
        for (int j=0;j<4;j++){
          f4 a = (j==0)?a0:((j==1)?a1:((j==2)?a2:a3));
          #pragma unroll
          for (int d=0; d<4; d++)
            acc[j][d] += a.x*w0[d] + a.y*w1[d] + a.z*w2[d] + a.w*w3[d];
        }
      }
    }
    #pragma unroll
    for (int j=0;j<4;j++){
      float v0=fmaxf(acc[j][0],0.f), v1=fmaxf(acc[j][1],0.f);
      float v2=fmaxf(acc[j][2],0.f), v3=fmaxf(acc[j][3],0.f);
      float s1 = v0+v1+v2+v3, s2 = v0*v0+v1*v1+v2*v2+v3*v3;
      for (int off=1; off<64; off<<=1){ s1 += __shfl_xor(s1, off); s2 += __shfl_xor(s2, off); }
      float mu = s1 * (1.f/256.f);
      float rs = rsqrtf(s2*(1.f/256.f) - mu*mu + 1e-5f);
      f4 o; o.x=(v0-mu)*rs; o.y=(v1-mu)*rs; o.z=(v2-mu)*rs; o.w=(v3-mu)*rs;
      *(f4*)(h1 + (tg*4+j)*260 + c4*4) = o;
    }

    float ac2[4][4];
    { f4 bv = *(const f4*)(b1 + c4*4);
      #pragma unroll
      for (int j=0;j<4;j++){ ac2[j][0]=bv.x; ac2[j][1]=bv.y; ac2[j][2]=bv.z; ac2[j][3]=bv.w; } }
    for (int kh=0; kh<8; ++kh){
      __syncthreads();
      { int c = tid;
        const f4* src = (const f4*)(W1 + c*256 + kh*32);
        #pragma unroll
        for (int q=0;q<8;q++){
          f4 v = src[q];
          Wt[(q*4+0)*256 + c] = v.x; Wt[(q*4+1)*256 + c] = v.y;
          Wt[(q*4+2)*256 + c] = v.z; Wt[(q*4+3)*256 + c] = v.w;
        }
      }
      __syncthreads();
      for (int kq=0; kq<8; kq++){
        int k0 = kh*32 + kq*4;
        f4 a0 = *(const f4*)(h1 + (tg*4+0)*260 + k0);
        f4 a1 = *(const f4*)(h1 + (tg*4+1)*260 + k0);
        f4 a2 = *(const f4*)(h1 + (tg*4+2)*260 + k0);
        f4 a3 = *(const f4*)(h1 + (tg*4+3)*260 + k0);
        f4 w0 = *(const f4*)(Wt + (kq*4+0)*256 + c4*4);
        f4 w1 = *(const f4*)(Wt + (kq*4+1)*256 + c4*4);
        f4 w2 = *(const f4*)(Wt + (kq*4+2)*256 + c4*4);
        f4 w3 = *(const f4*)(Wt + (kq*4+3)*256 + c4*4);
        #pragma unroll
        for (int j=0;j<4;j++){
          f4 a = (j==0)?a0:((j==1)?a1:((j==2)?a2:a3));
          #pragma unroll
          for (int d=0; d<4; d++)
            ac2[j][d] += a.x*w0[d] + a.y*w1[d] + a.z*w2[d] + a.w*w3[d];
        }
      }
    }
    #pragma unroll
    for (int j=0;j<4;j++){
      float v0=fmaxf(ac2[j][0],0.f), v1=fmaxf(ac2[j][1],0.f);
      float v2=fmaxf(ac2[j][2],0.f), v3=fmaxf(ac2[j][3],0.f);
      float s1 = v0+v1+v2+v3, s2 = v0*v0+v1*v1+v2*v2+v3*v3;
      for (int off=1; off<64; off<<=1){ s1 += __shfl_xor(s1, off); s2 += __shfl_xor(s2, off); }
      float mu = s1 * (1.f/256.f);
      float rs = rsqrtf(s2*(1.f/256.f) - mu*mu + 1e-5f);
      long tok = tok0 + tg*4 + j;
      long bb = tok >> 10, ss = tok & 1023;
      unsigned short* o = Xcat + (ss*128 + bb)*512 + br*256 + c4*4;
      unsigned lo = (unsigned)f2bf((v0-mu)*rs) | ((unsigned)f2bf((v1-mu)*rs) << 16);
      unsigned hi = (unsigned)f2bf((v2-mu)*rs) | ((unsigned)f2bf((v3-mu)*rs) << 16);
      ((unsigned*)o)[0] = lo; ((unsigned*)o)[1] = hi;
    }
  }
}

// ---------------- coalesced agent-scope poll load: 8 x dwordx4, sc1 ----------------
__device__ __forceinline__ void ld8x16_sc1(const unsigned* p, u32x4* v){
  asm volatile(
    "global_load_dwordx4 %0, %8, off sc1\n\t"
    "global_load_dwordx4 %1, %8, off offset:256 sc1\n\t"
    "global_load_dwordx4 %2, %8, off offset:512 sc1\n\t"
    "global_load_dwordx4 %3, %8, off offset:768 sc1\n\t"
    "global_load_dwordx4 %4, %8, off offset:1024 sc1\n\t"
    "global_load_dwordx4 %5, %8, off offset:1280 sc1\n\t"
    "global_load_dwordx4 %6, %8, off offset:1536 sc1\n\t"
    "global_load_dwordx4 %7, %8, off offset:1792 sc1\n\t"
    "s_waitcnt vmcnt(0)"
    : "=&v"(v[0]),"=&v"(v[1]),"=&v"(v[2]),"=&v"(v[3]),
      "=&v"(v[4]),"=&v"(v[5]),"=&v"(v[6]),"=&v"(v[7])
    : "v"(p) : "memory");
}

// ---------------- persistent LSTM kernel (tagged-word exchange, 16 WGs/group x 128 cols) ----------------
// grid = 128 WGs x 256 thr. group g = blockIdx&7 (16 batch rows), member m = blockIdx>>3 in [0,16).
// WG owns 128 gate-cols as two 64-col tiles (c=0,1). Broadcast fan-out of the group's h tile
// is 16 consumers (was 32) -> coherent read traffic halves. Poll/LDS-stage identical to r11.
__global__ void __launch_bounds__(256, 1) lstm_pk(
    const unsigned short* __restrict__ Xcat,
    const unsigned short* __restrict__ Wcat,
    const float* __restrict__ bias_cat,
    unsigned int* __restrict__ hw,
    unsigned int* __restrict__ ctr){
  __shared__ __align__(16) char actb[32768];   // h act tiles, double buffer (r11 layout)
  __shared__ int okf, sdead;
  int tid = threadIdx.x;
  int lane = tid & 63, w = tid >> 6;
  int g = blockIdx.x & 7, m = blockIdx.x >> 3;

  // stationary weights: two col-tiles; tile c covers cols 128m+64c+16w+(lane&15), k = s*32+(lane>>4)*8
  bf16x8 wf[64];
  {
    #pragma unroll
    for (int c=0;c<2;c++){
      int colg = 128*m + 64*c + 16*w + (lane & 15);
      const bf16x8* wsrc = (const bf16x8*)(Wcat + (long)colg*1024 + (lane>>4)*8);
      #pragma unroll
      for (int s=0;s<32;s++) wf[c*32+s] = wsrc[s*4];
    }
  }
  f32x4 bias4A, bias4B;
  {
    int cbA = 128*m + 16*w + 4*(lane>>4);
    int cbB = cbA + 64;
    bias4A.x = bias_cat[cbA+0]; bias4A.y = bias_cat[cbA+1];
    bias4A.z = bias_cat[cbA+2]; bias4A.w = bias_cat[cbA+3];
    bias4B.x = bias_cat[cbB+0]; bias4B.y = bias_cat[cbB+1];
    bias4B.z = bias_cat[cbB+2]; bias4B.w = bias_cat[cbB+3];
  }

  // co-residency check (128 WGs; bounded, no hang)
  if (tid == 0){
    __hip_atomic_fetch_add(&ctr[255], 1u, __ATOMIC_RELAXED, __HIP_MEMORY_SCOPE_AGENT);
    unsigned v = 0; int it = 0;
    do {
      v = __hip_atomic_load(&ctr[255], __ATOMIC_RELAXED, __HIP_MEMORY_SCOPE_AGENT);
      if (v >= 128u) break;
      __builtin_amdgcn_s_sleep(8);
    } while (++it < 2000000);
    okf = (v >= 128u) ? 1 : 0;
    sdead = 0;
  }
  __syncthreads();
  if (!okf) return;

  float cstA = 0.f, cstB = 0.f;
  int r16 = tid >> 4, q16 = tid & 15;

  // prologue: x-part for t=0, both tiles
  f32x4 aA0, aA1, aB0, aB1;
  {
    bf16x8 xf[16];
    const bf16x8* xsrc = (const bf16x8*)(Xcat + ((long)0*128 + g*16 + (lane&15))*512 + (lane>>4)*8);
    #pragma unroll
    for (int s=0;s<16;s++) xf[s] = xsrc[s*4];
    aA0 = bias4A; aA1.x=0.f; aA1.y=0.f; aA1.z=0.f; aA1.w=0.f;
    aB0 = bias4B; aB1.x=0.f; aB1.y=0.f; aB1.z=0.f; aB1.w=0.f;
    #pragma unroll
    for (int s=0;s<16;s+=2){
      aA0 = __builtin_amdgcn_mfma_f32_16x16x32_bf16(wf[s],    xf[s],   aA0, 0, 0, 0);
      aA1 = __builtin_amdgcn_mfma_f32_16x16x32_bf16(wf[s+1],  xf[s+1], aA1, 0, 0, 0);
      aB0 = __builtin_amdgcn_mfma_f32_16x16x32_bf16(wf[32+s], xf[s],   aB0, 0, 0, 0);
      aB1 = __builtin_amdgcn_mfma_f32_16x16x32_bf16(wf[33+s], xf[s+1], aB1, 0, 0, 0);
    }
  }

  #pragma unroll 1
  for (int t=0; t<1024; ++t){
    // ---- poll own 32 tagged words; stage to LDS (r11-identical layout) ----
    if (t == 0){
      char* hl = actb;                      // h_0 = 0
      #pragma unroll
      for (int i=0;i<8;i++){
        int byt = (r16*1024 + q16*8 + i*128) ^ ((r16 & 7) << 4);
        *(ull*)(hl + byt) = 0ull;
      }
    } else {
      const unsigned* hp = hw + ((long)(t&1)*65536) + g*8192 + r16*512 + q16*4;
      u32x4 hv[8];
      unsigned tt = (unsigned)t; int itc = 0;
      for (;;){
        ld8x16_sc1(hp, hv);
        unsigned bad = 0;
        #pragma unroll
        for (int i=0;i<8;i++){
          bad |= (hv[i].x & 0xFFFFu) ^ tt;
          bad |= (hv[i].y & 0xFFFFu) ^ tt;
          bad |= (hv[i].z & 0xFFFFu) ^ tt;
          bad |= (hv[i].w & 0xFFFFu) ^ tt;
        }
        if (!bad) break;
        if ((itc & 31) == 31 && *(volatile int*)&sdead) break;
        if (++itc > 200000){
          *(volatile int*)&sdead = 1;
          __hip_atomic_store(&ctr[252], tt, __ATOMIC_RELAXED, __HIP_MEMORY_SCOPE_AGENT);
          break;
        }
      }
      char* hl = actb + (t&1)*16384;
      #pragma unroll
      for (int i=0;i<8;i++){
        unsigned p0 = (hv[i].x >> 16) | (hv[i].y & 0xFFFF0000u);
        unsigned p1 = (hv[i].z >> 16) | (hv[i].w & 0xFFFF0000u);
        ull pp = (ull)p0 | ((ull)p1 << 32);
        int byt = (r16*1024 + q16*8 + i*128) ^ ((r16 & 7) << 4);
        *(ull*)(hl + byt) = pp;
      }
    }
    __syncthreads();
    if (*(volatile int*)&sdead) break;
    // ---- h-part MFMAs (k=512..1023), both col-tiles share B-fragments ----
    {
      const char* hl = actb + (t&1)*16384;
      #pragma unroll
      for (int s=0;s<16;s+=2){
        int by0 = ((lane&15)*1024 + s*64     + (lane>>4)*16) ^ (((lane&15)&7) << 4);
        int by1 = ((lane&15)*1024 + (s+1)*64 + (lane>>4)*16) ^ (((lane&15)&7) << 4);
        bf16x8 b0 = *(const bf16x8*)(hl + by0);
        bf16x8 b1 = *(const bf16x8*)(hl + by1);
        aA0 = __builtin_amdgcn_mfma_f32_16x16x32_bf16(wf[16+s], b0, aA0, 0, 0, 0);
        aA1 = __builtin_amdgcn_mfma_f32_16x16x32_bf16(wf[17+s], b1, aA1, 0, 0, 0);
        aB0 = __builtin_amdgcn_mfma_f32_16x16x32_bf16(wf[48+s], b0, aB0, 0, 0, 0);
        aB1 = __builtin_amdgcn_mfma_f32_16x16x32_bf16(wf[49+s], b1, aB1, 0, 0, 0);
      }
    }
    // ---- gates & state update (two units per lane) ----
    unsigned wordA, wordB;
    {
      float gi = aA0.x + aA1.x, gf = aA0.y + aA1.y;
      float gg = aA0.z + aA1.z, go = aA0.w + aA1.w;
      float iv = 1.f / (1.f + __expf(-gi));
      float fv = 1.f / (1.f + __expf(-gf));
      float e2 = __expf(-2.f * gg);
      float gv = (1.f - e2) / (1.f + e2);
      float ov = 1.f / (1.f + __expf(-go));
      cstA = fv * cstA + iv * gv;
      float e2c = __expf(-2.f * cstA);
      float hout = ov * (1.f - e2c) / (1.f + e2c);
      wordA = ((unsigned)f2bf(hout) << 16) | (unsigned)((t+1) & 0xFFFF);
    }
    {
      float gi = aB0.x + aB1.x, gf = aB0.y + aB1.y;
      float gg = aB0.z + aB1.z, go = aB0.w + aB1.w;
      float iv = 1.f / (1.f + __expf(-gi));
      float fv = 1.f / (1.f + __expf(-gf));
      float e2 = __expf(-2.f * gg);
      float gv = (1.f - e2) / (1.f + e2);
      float ov = 1.f / (1.f + __expf(-go));
      cstB = fv * cstB + iv * gv;
      float e2c = __expf(-2.f * cstB);
      float hout = ov * (1.f - e2c) / (1.f + e2c);
      wordB = ((unsigned)f2bf(hout) << 16) | (unsigned)((t+1) & 0xFFFF);
    }
    // ---- publish h_{t+1}: two tagged words per lane (fire-and-forget) ----
    {
      int row  = lane & 15;
      int unitA = 32*m + 4*w + (lane >> 4);
      int unitB = unitA + 16;
      unsigned int* base = hw + ((long)((t+1)&1)*65536) + g*8192 + row*512;
      __hip_atomic_store(base + unitA, wordA, __ATOMIC_RELAXED, __HIP_MEMORY_SCOPE_AGENT);
      __hip_atomic_store(base + unitB, wordB, __ATOMIC_RELAXED, __HIP_MEMORY_SCOPE_AGENT);
    }
    // ---- x-part for t+1 (overlaps store visibility) ----
    {
      int tn = (t < 1023) ? (t+1) : 1023;
      bf16x8 xf[16];
      const bf16x8* xsrc = (const bf16x8*)(Xcat + ((long)tn*128 + g*16 + (lane&15))*512 + (lane>>4)*8);
      #pragma unroll
      for (int s=0;s<16;s++) xf[s] = xsrc[s*4];
      aA0 = bias4A; aA1.x=0.f; aA1.y=0.f; aA1.z=0.f; aA1.w=0.f;
      aB0 = bias4B; aB1.x=0.f; aB1.y=0.f; aB1.z=0.f; aB1.w=0.f;
      #pragma unroll
      for (int s=0;s<16;s+=2){
        aA0 = __builtin_amdgcn_mfma_f32_16x16x32_bf16(wf[s],    xf[s],   aA0, 0, 0, 0);
        aA1 = __builtin_amdgcn_mfma_f32_16x16x32_bf16(wf[s+1],  xf[s+1], aA1, 0, 0, 0);
        aB0 = __builtin_amdgcn_mfma_f32_16x16x32_bf16(wf[32+s], xf[s],   aB0, 0, 0, 0);
        aB1 = __builtin_amdgcn_mfma_f32_16x16x32_bf16(wf[33+s], xf[s+1], aB1, 0, 0, 0);
      }
    }
  }

  __syncthreads();
  if (tid == 0 && !sdead)
    __hip_atomic_fetch_add(&ctr[251], 1u, __ATOMIC_RELAXED, __HIP_MEMORY_SCOPE_AGENT);
}

// ---------------- output projection (reads tagged words, parity 0) ----------------
__global__ void __launch_bounds__(256) out_gemm(
    const unsigned int* __restrict__ hw, const unsigned int* __restrict__ ctr,
    const float* __restrict__ out_w, const float* __restrict__ out_b,
    float* __restrict__ out){
  unsigned done = ctr[251], arriv = ctr[255], dead = ctr[252];
  if (dead != 0u || done != 128u){
    float v = dead ? (20000.f + (float)dead) : (10000.f + (float)arriv);
    if (threadIdx.x < 32) out[blockIdx.x*32 + threadIdx.x] = v;
    return;
  }
  __shared__ float part[8][32];
  int b = blockIdx.x;
  int g = b >> 4, r = b & 15;
  const unsigned int* hrow = hw + (long)g*8192 + r*512;   // parity 0 holds h after step 1024
  int col = threadIdx.x & 31, p = threadIdx.x >> 5;
  float s = 0.f;
  for (int u = p*64; u < p*64 + 64; ++u)
    s += bf2f((unsigned short)(hrow[u] >> 16)) * out_w[col*512 + u];
  part[p][col] = s;
  __syncthreads();
  if (p == 0){
    float t = out_b[col];
    #pragma unroll
    for (int i=0;i<8;i++) t += part[i][col];
    out[b*32 + col] = t;
  }
}

extern "C" void kernel_launch(void* const* d_in, const int* in_sizes, int n_in,
                              void* d_out, int out_size, void* d_ws, size_t ws_size,
                              hipStream_t stream){
  const float* x_num   = (const float*)d_in[0];
  const int*   x_state = (const int*)d_in[1];
  const float* num_w0  = (const float*)d_in[2];
  const float* num_b0  = (const float*)d_in[3];
  const float* num_w1  = (const float*)d_in[4];
  const float* num_b1  = (const float*)d_in[5];
  const float* emb     = (const float*)d_in[6];
  const float* st_w0   = (const float*)d_in[7];
  const float* st_b0   = (const float*)d_in[8];
  const float* st_w1   = (const float*)d_in[9];
  const float* st_b1   = (const float*)d_in[10];
  const float* Wii = (const float*)d_in[11];
  const float* Whi = (const float*)d_in[12];
  const float* Wif = (const float*)d_in[13];
  const float* Whf = (const float*)d_in[14];
  const float* Wig = (const float*)d_in[15];
  const float* Whg = (const float*)d_in[16];
  const float* Wio = (const float*)d_in[17];
  const float* Who = (const float*)d_in[18];
  const float* Bii = (const float*)d_in[19];
  const float* Bhi = (const float*)d_in[20];
  const float* Bif = (const float*)d_in[21];
  const float* Bhf = (const float*)d_in[22];
  const float* Big = (const float*)d_in[23];
  const float* Bhg = (const float*)d_in[24];
  const float* Bio = (const float*)d_in[25];
  const float* Bho = (const float*)d_in[26];
  const float* out_w = (const float*)d_in[27];
  const float* out_b = (const float*)d_in[28];

  float* out = (float*)d_out;

  // sentinel: if later launches silently fail, absmax ~= 50000
  diag_write<<<16, 256, 0, stream>>>(out, 50000.f);

  if (ws_size < WS_NEED){
    diag_write<<<16, 256, 0, stream>>>(out, 100000.f + (float)(ws_size >> 20));
    return;
  }

  char* ws = (char*)d_ws;
  unsigned short* Xcat = (unsigned short*)(ws + OFF_XCAT);
  unsigned short* Wcat = (unsigned short*)(ws + OFF_WCAT);
  float* bias_cat      = (float*)(ws + OFF_BIAS);
  unsigned int* hw     = (unsigned int*)(ws + OFF_HW);
  unsigned int* ctr    = (unsigned int*)(ws + OFF_CTR);

  // zero tagged-word h buffer + counters every call (tags restart; h_0 = 0 with tag 0)
  hipMemsetAsync(ws + OFF_HW, 0, 524288 + 1024, stream);

  prep_w<<<8192, 256, 0, stream>>>(Wii, Wif, Wig, Wio, Whi, Whf, Whg, Who,
                                   Bii, Bif, Big, Bio, Bhi, Bhf, Bhg, Bho,
                                   Wcat, bias_cat);

  stageA_fused<<<8192, 256, 0, stream>>>(x_num, x_state, emb,
                                         num_w0, num_b0, num_w1, num_b1,
                                         st_w0, st_b0, st_w1, st_b1, Xcat);

  lstm_pk<<<128, 256, 0, stream>>>(Xcat, Wcat, bias_cat, hw, ctr);

  out_gemm<<<128, 256, 0, stream>>>(hw, ctr, out_w, out_b, out);
}

// Round 15
// 5348.895 us; speedup vs baseline: 2.6469x; 1.2937x over previous
//
#include <hip/hip_runtime.h>
#include <hip/hip_bf16.h>

typedef __attribute__((ext_vector_type(4))) float f4;
typedef __attribute__((ext_vector_type(4))) float f32x4;
typedef __attribute__((ext_vector_type(8))) short bf16x8;
typedef __attribute__((ext_vector_type(4))) unsigned u32x4;
typedef unsigned long long ull;

// ---------------- workspace layout (bytes) ----------------
#define OFF_XCAT   0ull                 // ushort [1024][128][512]  time-major LSTM input
#define OFF_WCAT   134217728ull         // ushort [2048][1024]      packed LSTM weights
#define OFF_BIAS   138412032ull         // float  [2048]
#define OFF_HW     138420224ull         // uint   [2][8][16][512]   tagged h words: (h_bf16<<16)|step_tag
#define OFF_CTR    138944512ull         // uint   [256]             counters/diag
#define WS_NEED    138945536ull

__device__ inline unsigned short f2bf(float x){
  unsigned u = __float_as_uint(x);
  unsigned r = (u + 0x7FFFu + ((u >> 16) & 1u)) >> 16;   // RNE
  return (unsigned short)r;
}
__device__ inline float bf2f(unsigned short s){ return __uint_as_float(((unsigned)s) << 16); }

// ---------------- diagnostic fill (absmax is the debug channel) ----------------
__global__ void __launch_bounds__(256) diag_write(float* out, float val){
  out[blockIdx.x * 256 + threadIdx.x] = val;
}

// ---------------- weight repack ----------------
__global__ void __launch_bounds__(256) prep_w(
    const float* Wii, const float* Wif, const float* Wig, const float* Wio,
    const float* Whi, const float* Whf, const float* Whg, const float* Who,
    const float* Bii, const float* Bif, const float* Big, const float* Bio,
    const float* Bhi, const float* Bhf, const float* Bhg, const float* Bho,
    unsigned short* Wcat, float* bias_cat){
  int e = blockIdx.x * 256 + threadIdx.x;        // < 2048*1024
  int col = e >> 10, k = e & 1023;
  int u = col >> 2, g = col & 3;
  float v;
  if (k < 512){
    const float* p = (g==0)?Wii:((g==1)?Wif:((g==2)?Wig:Wio));
    v = p[u*512 + k];
  } else {
    const float* p = (g==0)?Whi:((g==1)?Whf:((g==2)?Whg:Who));
    v = p[u*512 + (k-512)];
  }
  Wcat[e] = f2bf(v);
  if (e < 2048){
    int u2 = e >> 2, g2 = e & 3;
    const float* bx = (g2==0)?Bii:((g2==1)?Bif:((g2==2)?Big:Bio));
    const float* bh = (g2==0)?Bhi:((g2==1)?Bhf:((g2==2)?Bhg:Bho));
    bias_cat[e] = bx[u2] + bh[u2];
  }
}

// ---------------- fused stage A (proven r2/r3) ----------------
__global__ void __launch_bounds__(256) stageA_fused(
    const float* __restrict__ xnum, const int* __restrict__ xstate,
    const float* __restrict__ emb,
    const float* __restrict__ num_w0, const float* __restrict__ num_b0,
    const float* __restrict__ num_w1, const float* __restrict__ num_b1,
    const float* __restrict__ st_w0,  const float* __restrict__ st_b0,
    const float* __restrict__ st_w1,  const float* __restrict__ st_b1,
    unsigned short* __restrict__ Xcat){
  __shared__ float Wt[32*256];
  __shared__ float xb[16*68];
  __shared__ float h1[16*260];
  int tid = threadIdx.x;
  long tok0 = (long)blockIdx.x * 16;
  int tg = tid >> 6, c4 = tid & 63;

  #pragma unroll 1
  for (int br = 0; br < 2; ++br){
    const float* W0 = br ? st_w0 : num_w0;
    const float* b0 = br ? st_b0 : num_b0;
    const float* W1 = br ? st_w1 : num_w1;
    const float* b1 = br ? st_b1 : num_b1;

    __syncthreads();
    if (br == 0){
      int tk = tid >> 4, q = tid & 15;
      f4 v = *(const f4*)(xnum + (tok0+tk)*64 + q*4);
      float* d = xb + tk*68 + q*4;
      d[0]=v.x; d[1]=v.y; d[2]=v.z; d[3]=v.w;
    } else {
      int tk = tid >> 4, j = tid & 15;
      int idx = xstate[(tok0+tk)*16 + j];
      f4 v = *(const f4*)(emb + idx*4);
      float* d = xb + tk*68 + j*4;
      d[0]=v.x; d[1]=v.y; d[2]=v.z; d[3]=v.w;
    }

    float acc[4][4];
    { f4 bv = *(const f4*)(b0 + c4*4);
      #pragma unroll
      for (int j=0;j<4;j++){ acc[j][0]=bv.x; acc[j][1]=bv.y; acc[j][2]=bv.z; acc[j][3]=bv.w; } }
    for (int kh=0; kh<2; ++kh){
      __syncthreads();
      { int c = tid;
        const f4* src = (const f4*)(W0 + c*64 + kh*32);
        #pragma unroll
        for (int q=0;q<8;q++){
          f4 v = src[q];
          Wt[(q*4+0)*256 + c] = v.x; Wt[(q*4+1)*256 + c] = v.y;
          Wt[(q*4+2)*256 + c] = v.z; Wt[(q*4+3)*256 + c] = v.w;
        }
      }
      __syncthreads();
      for (int kq=0; kq<8; kq++){
        int k0 = kh*32 + kq*4;
        f4 a0 = *(const f4*)(xb + (tg*4+0)*68 + k0);
        f4 a1 = *(const f4*)(xb + (tg*4+1)*68 + k0);
        f4 a2 = *(const f4*)(xb + (tg*4+2)*68 + k0);
        f4 a3 = *(const f4*)(xb + (tg*4+3)*68 + k0);
        f4 w0 = *(const f4*)(Wt + (kq*4+0)*256 + c4*4);
        f4 w1 = *(const f4*)(Wt + (kq*4+1)*256 + c4*4);
        f4 w2 = *(const f4*)(Wt + (kq*4+2)*256 + c4*4);
        f4 w3 = *(const f4*)(Wt + (kq*4+3)*256 + c4*4);
        #pragma unroll
        for (int j=0;j<4;j++){
          f4 a = (j==0)?a0:((j==1)?a1:((j==2)?a2:a3));
          #pragma unroll
          for (int d=0; d<4; d++)
            acc[j][d] += a.x*w0[d] + a.y*w1[d] + a.z*w2[d] + a.w*w3[d];
        }
      }
    }
    #pragma unroll
    for (int j=0;j<4;j++){
      float v0=fmaxf(acc[j][0],0.f), v1=fmaxf(acc[j][1],0.f);
      float v2=fmaxf(acc[j][2],0.f), v3=fmaxf(acc[j][3],0.f);
      float s1 = v0+v1+v2+v3, s2 = v0*v0+v1*v1+v2*v2+v3*v3;
      for (int off=1; off<64; off<<=1){ s1 += __shfl_xor(s1, off); s2 += __shfl_xor(s2, off); }
      float mu = s1 * (1.f/256.f);
      float rs = rsqrtf(s2*(1.f/256.f) - mu*mu + 1e-5f);
      f4 o; o.x=(v0-mu)*rs; o.y=(v1-mu)*rs; o.z=(v2-mu)*rs; o.w=(v3-mu)*rs;
      *(f4*)(h1 + (tg*4+j)*260 + c4*4) = o;
    }

    float ac2[4][4];
    { f4 bv = *(const f4*)(b1 + c4*4);
      #pragma unroll
      for (int j=0;j<4;j++){ ac2[j][0]=bv.x; ac2[j][1]=bv.y; ac2[j][2]=bv.z; ac2[j][3]=bv.w; } }
    for (int kh=0; kh<8; ++kh){
      __syncthreads();
      { int c = tid;
        const f4* src = (const f4*)(W1 + c*256 + kh*32);
        #pragma unroll
        for (int q=0;q<8;q++){
          f4 v = src[q];
          Wt[(q*4+0)*256 + c] = v.x; Wt[(q*4+1)*256 + c] = v.y;
          Wt[(q*4+2)*256 + c] = v.z; Wt[(q*4+3)*256 + c] = v.w;
        }
      }
      __syncthreads();
      for (int kq=0; kq<8; kq++){
        int k0 = kh*32 + kq*4;
        f4 a0 = *(const f4*)(h1 + (tg*4+0)*260 + k0);
        f4 a1 = *(const f4*)(h1 + (tg*4+1)*260 + k0);
        f4 a2 = *(const f4*)(h1 + (tg*4+2)*260 + k0);
        f4 a3 = *(const f4*)(h1 + (tg*4+3)*260 + k0);
        f4 w0 = *(const f4*)(Wt + (kq*4+0)*256 + c4*4);
        f4 w1 = *(const f4*)(Wt + (kq*4+1)*256 + c4*4);
        f4 w2 = *(const f4*)(Wt + (kq*4+2)*256 + c4*4);
        f4 w3 = *(const f4*)(Wt + (kq*4+3)*256 + c4*4);
        #pragma unroll
        for (int j=0;j<4;j++){
          f4 a = (j==0)?a0:((j==1)?a1:((j==2)?a2:a3));
          #pragma unroll
          for (int d=0; d<4; d++)
            ac2[j][d] += a.x*w0[d] + a.y*w1[d] + a.z*w2[d] + a.w*w3[d];
        }
      }
    }
    #pragma unroll
    for (int j=0;j<4;j++){
      float v0=fmaxf(ac2[j][0],0.f), v1=fmaxf(ac2[j][1],0.f);
      float v2=fmaxf(ac2[j][2],0.f), v3=fmaxf(ac2[j][3],0.f);
      float s1 = v0+v1+v2+v3, s2 = v0*v0+v1*v1+v2*v2+v3*v3;
      for (int off=1; off<64; off<<=1){ s1 += __shfl_xor(s1, off); s2 += __shfl_xor(s2, off); }
      float mu = s1 * (1.f/256.f);
      float rs = rsqrtf(s2*(1.f/256.f) - mu*mu + 1e-5f);
      long tok = tok0 + tg*4 + j;
      long bb = tok >> 10, ss = tok & 1023;
      unsigned short* o = Xcat + (ss*128 + bb)*512 + br*256 + c4*4;
      unsigned lo = (unsigned)f2bf((v0-mu)*rs) | ((unsigned)f2bf((v1-mu)*rs) << 16);
      unsigned hi = (unsigned)f2bf((v2-mu)*rs) | ((unsigned)f2bf((v3-mu)*rs) << 16);
      ((unsigned*)o)[0] = lo; ((unsigned*)o)[1] = hi;
    }
  }
}

// ---------------- coalesced agent-scope poll load: 8 x dwordx4, sc1 ----------------
__device__ __forceinline__ void ld8x16_sc1(const unsigned* p, u32x4* v){
  asm volatile(
    "global_load_dwordx4 %0, %8, off sc1\n\t"
    "global_load_dwordx4 %1, %8, off offset:256 sc1\n\t"
    "global_load_dwordx4 %2, %8, off offset:512 sc1\n\t"
    "global_load_dwordx4 %3, %8, off offset:768 sc1\n\t"
    "global_load_dwordx4 %4, %8, off offset:1024 sc1\n\t"
    "global_load_dwordx4 %5, %8, off offset:1280 sc1\n\t"
    "global_load_dwordx4 %6, %8, off offset:1536 sc1\n\t"
    "global_load_dwordx4 %7, %8, off offset:1792 sc1\n\t"
    "s_waitcnt vmcnt(0)"
    : "=&v"(v[0]),"=&v"(v[1]),"=&v"(v[2]),"=&v"(v[3]),
      "=&v"(v[4]),"=&v"(v[5]),"=&v"(v[6]),"=&v"(v[7])
    : "v"(p) : "memory");
}

// ---------------- persistent LSTM kernel (r11 structure + LDS-resident h-weights) ----------------
// grid = 256 WGs x 256 thr. group g = blockIdx&7 (16 batch rows), member m = blockIdx>>3.
// h-part weights (critical path) live in LDS as per-lane private spill (lane writes/reads
// its own fragments at w*16384 + s*1024 + lane*16 — no sharing, 2-way bank alias = free).
// x-part weights (post-publish, latency tolerant) stay in registers/L2. Rest = r11 verbatim.
__global__ void __launch_bounds__(256, 1) lstm_pk(
    const unsigned short* __restrict__ Xcat,
    const unsigned short* __restrict__ Wcat,
    const float* __restrict__ bias_cat,
    unsigned int* __restrict__ hw,
    unsigned int* __restrict__ ctr){
  __shared__ __align__(16) char actb[32768];   // h act tiles, double buffer (r11 layout)
  extern __shared__ __align__(16) char wlds[]; // 64KB: h-part weights, per-lane fragments
  __shared__ int okf, sdead;
  int tid = threadIdx.x;
  int lane = tid & 63, w = tid >> 6;
  int g = blockIdx.x & 7, m = blockIdx.x >> 3;

  // weights: cols 64m+16w+(lane&15), k = s*32+(lane>>4)*8
  int colg = 64*m + 16*w + (lane & 15);
  bf16x8 wfx[16];
  {
    const bf16x8* wsrc = (const bf16x8*)(Wcat + (long)colg*1024 + (lane>>4)*8);
    #pragma unroll
    for (int s=0;s<16;s++) wfx[s] = wsrc[s*4];            // x-part (k=0..511)
    #pragma unroll
    for (int s=0;s<16;s++){                               // h-part -> LDS private spill
      bf16x8 v = wsrc[(16+s)*4];
      *(bf16x8*)(wlds + w*16384 + s*1024 + lane*16) = v;
    }
  }
  int cb = 64*m + 16*w + 4*(lane>>4);
  f32x4 bias4;
  bias4.x = bias_cat[cb+0]; bias4.y = bias_cat[cb+1];
  bias4.z = bias_cat[cb+2]; bias4.w = bias_cat[cb+3];

  // co-residency check (bounded; no hang)
  if (tid == 0){
    __hip_atomic_fetch_add(&ctr[255], 1u, __ATOMIC_RELAXED, __HIP_MEMORY_SCOPE_AGENT);
    unsigned v = 0; int it = 0;
    do {
      v = __hip_atomic_load(&ctr[255], __ATOMIC_RELAXED, __HIP_MEMORY_SCOPE_AGENT);
      if (v >= 256u) break;
      __builtin_amdgcn_s_sleep(8);
    } while (++it < 2000000);
    okf = (v >= 256u) ? 1 : 0;
    sdead = 0;
  }
  __syncthreads();
  if (!okf) return;

  float cst = 0.f;
  int r16 = tid >> 4, q16 = tid & 15;
  const char* wl = wlds + w*16384 + lane*16;

  // prologue: x-part for t=0
  f32x4 acc0, acc1;
  {
    bf16x8 xf[16];
    const bf16x8* xsrc = (const bf16x8*)(Xcat + ((long)0*128 + g*16 + (lane&15))*512 + (lane>>4)*8);
    #pragma unroll
    for (int s=0;s<16;s++) xf[s] = xsrc[s*4];
    acc0 = bias4;
    acc1.x=0.f; acc1.y=0.f; acc1.z=0.f; acc1.w=0.f;
    #pragma unroll
    for (int s=0;s<16;s+=2){
      acc0 = __builtin_amdgcn_mfma_f32_16x16x32_bf16(wfx[s],   xf[s],   acc0, 0, 0, 0);
      acc1 = __builtin_amdgcn_mfma_f32_16x16x32_bf16(wfx[s+1], xf[s+1], acc1, 0, 0, 0);
    }
  }

  #pragma unroll 1
  for (int t=0; t<1024; ++t){
    // ---- poll own 32 tagged words; stage to LDS (r11-identical layout) ----
    if (t == 0){
      char* hl = actb;                      // h_0 = 0
      #pragma unroll
      for (int i=0;i<8;i++){
        int byt = (r16*1024 + q16*8 + i*128) ^ ((r16 & 7) << 4);
        *(ull*)(hl + byt) = 0ull;
      }
    } else {
      const unsigned* hp = hw + ((long)(t&1)*65536) + g*8192 + r16*512 + q16*4;
      u32x4 hv[8];
      unsigned tt = (unsigned)t; int itc = 0;
      for (;;){
        ld8x16_sc1(hp, hv);
        unsigned bad = 0;
        #pragma unroll
        for (int i=0;i<8;i++){
          bad |= (hv[i].x & 0xFFFFu) ^ tt;
          bad |= (hv[i].y & 0xFFFFu) ^ tt;
          bad |= (hv[i].z & 0xFFFFu) ^ tt;
          bad |= (hv[i].w & 0xFFFFu) ^ tt;
        }
        if (!bad) break;
        if ((itc & 31) == 31 && *(volatile int*)&sdead) break;
        if (++itc > 200000){
          *(volatile int*)&sdead = 1;
          __hip_atomic_store(&ctr[252], tt, __ATOMIC_RELAXED, __HIP_MEMORY_SCOPE_AGENT);
          break;
        }
      }
      char* hl = actb + (t&1)*16384;
      #pragma unroll
      for (int i=0;i<8;i++){
        unsigned p0 = (hv[i].x >> 16) | (hv[i].y & 0xFFFF0000u);
        unsigned p1 = (hv[i].z >> 16) | (hv[i].w & 0xFFFF0000u);
        ull pp = (ull)p0 | ((ull)p1 << 32);
        int byt = (r16*1024 + q16*8 + i*128) ^ ((r16 & 7) << 4);
        *(ull*)(hl + byt) = pp;
      }
    }
    __syncthreads();
    if (*(volatile int*)&sdead) break;
    // ---- h-part MFMAs (k=512..1023), weights from LDS (private fragments) ----
    {
      const char* hl = actb + (t&1)*16384;
      #pragma unroll
      for (int s=0;s<16;s+=2){
        bf16x8 wb0 = *(const bf16x8*)(wl + s*1024);
        bf16x8 wb1 = *(const bf16x8*)(wl + (s+1)*1024);
        int by0 = ((lane&15)*1024 + s*64     + (lane>>4)*16) ^ (((lane&15)&7) << 4);
        int by1 = ((lane&15)*1024 + (s+1)*64 + (lane>>4)*16) ^ (((lane&15)&7) << 4);
        bf16x8 b0 = *(const bf16x8*)(hl + by0);
        bf16x8 b1 = *(const bf16x8*)(hl + by1);
        acc0 = __builtin_amdgcn_mfma_f32_16x16x32_bf16(wb0, b0, acc0, 0, 0, 0);
        acc1 = __builtin_amdgcn_mfma_f32_16x16x32_bf16(wb1, b1, acc1, 0, 0, 0);
      }
    }
    // ---- gates & state update ----
    float gi = acc0.x + acc1.x, gf = acc0.y + acc1.y;
    float gg = acc0.z + acc1.z, go = acc0.w + acc1.w;
    float iv = 1.f / (1.f + __expf(-gi));
    float fv = 1.f / (1.f + __expf(-gf));
    float e2 = __expf(-2.f * gg);
    float gv = (1.f - e2) / (1.f + e2);
    float ov = 1.f / (1.f + __expf(-go));
    cst = fv * cst + iv * gv;
    float e2c = __expf(-2.f * cst);
    float hout = ov * (1.f - e2c) / (1.f + e2c);
    // ---- publish h_{t+1} as tagged word (fire-and-forget) ----
    {
      unsigned short hb16 = f2bf(hout);
      int unit = 16*m + 4*w + (lane >> 4);
      int row  = lane & 15;
      unsigned word = ((unsigned)hb16 << 16) | (unsigned)((t+1) & 0xFFFF);
      unsigned int* dst = hw + ((long)((t+1)&1)*65536) + g*8192 + row*512 + unit;
      __hip_atomic_store(dst, word, __ATOMIC_RELAXED, __HIP_MEMORY_SCOPE_AGENT);
    }
    // ---- x-part for t+1 (overlaps store visibility across the group) ----
    {
      int tn = (t < 1023) ? (t+1) : 1023;
      bf16x8 xf[16];
      const bf16x8* xsrc = (const bf16x8*)(Xcat + ((long)tn*128 + g*16 + (lane&15))*512 + (lane>>4)*8);
      #pragma unroll
      for (int s=0;s<16;s++) xf[s] = xsrc[s*4];
      acc0 = bias4;
      acc1.x=0.f; acc1.y=0.f; acc1.z=0.f; acc1.w=0.f;
      #pragma unroll
      for (int s=0;s<16;s+=2){
        acc0 = __builtin_amdgcn_mfma_f32_16x16x32_bf16(wfx[s],   xf[s],   acc0, 0, 0, 0);
        acc1 = __builtin_amdgcn_mfma_f32_16x16x32_bf16(wfx[s+1], xf[s+1], acc1, 0, 0, 0);
      }
    }
  }

  __syncthreads();
  if (tid == 0 && !sdead)
    __hip_atomic_fetch_add(&ctr[251], 1u, __ATOMIC_RELAXED, __HIP_MEMORY_SCOPE_AGENT);
}

// ---------------- output projection (reads tagged words, parity 0) ----------------
__global__ void __launch_bounds__(256) out_gemm(
    const unsigned int* __restrict__ hw, const unsigned int* __restrict__ ctr,
    const float* __restrict__ out_w, const float* __restrict__ out_b,
    float* __restrict__ out){
  unsigned done = ctr[251], arriv = ctr[255], dead = ctr[252];
  if (dead != 0u || done != 256u){
    float v = dead ? (20000.f + (float)dead) : (10000.f + (float)arriv);
    if (threadIdx.x < 32) out[blockIdx.x*32 + threadIdx.x] = v;
    return;
  }
  __shared__ float part[8][32];
  int b = blockIdx.x;
  int g = b >> 4, r = b & 15;
  const unsigned int* hrow = hw + (long)g*8192 + r*512;   // parity 0 holds h after step 1024
  int col = threadIdx.x & 31, p = threadIdx.x >> 5;
  float s = 0.f;
  for (int u = p*64; u < p*64 + 64; ++u)
    s += bf2f((unsigned short)(hrow[u] >> 16)) * out_w[col*512 + u];
  part[p][col] = s;
  __syncthreads();
  if (p == 0){
    float t = out_b[col];
    #pragma unroll
    for (int i=0;i<8;i++) t += part[i][col];
    out[b*32 + col] = t;
  }
}

extern "C" void kernel_launch(void* const* d_in, const int* in_sizes, int n_in,
                              void* d_out, int out_size, void* d_ws, size_t ws_size,
                              hipStream_t stream){
  const float* x_num   = (const float*)d_in[0];
  const int*   x_state = (const int*)d_in[1];
  const float* num_w0  = (const float*)d_in[2];
  const float* num_b0  = (const float*)d_in[3];
  const float* num_w1  = (const float*)d_in[4];
  const float* num_b1  = (const float*)d_in[5];
  const float* emb     = (const float*)d_in[6];
  const float* st_w0   = (const float*)d_in[7];
  const float* st_b0   = (const float*)d_in[8];
  const float* st_w1   = (const float*)d_in[9];
  const float* st_b1   = (const float*)d_in[10];
  const float* Wii = (const float*)d_in[11];
  const float* Whi = (const float*)d_in[12];
  const float* Wif = (const float*)d_in[13];
  const float* Whf = (const float*)d_in[14];
  const float* Wig = (const float*)d_in[15];
  const float* Whg = (const float*)d_in[16];
  const float* Wio = (const float*)d_in[17];
  const float* Who = (const float*)d_in[18];
  const float* Bii = (const float*)d_in[19];
  const float* Bhi = (const float*)d_in[20];
  const float* Bif = (const float*)d_in[21];
  const float* Bhf = (const float*)d_in[22];
  const float* Big = (const float*)d_in[23];
  const float* Bhg = (const float*)d_in[24];
  const float* Bio = (const float*)d_in[25];
  const float* Bho = (const float*)d_in[26];
  const float* out_w = (const float*)d_in[27];
  const float* out_b = (const float*)d_in[28];

  float* out = (float*)d_out;

  // sentinel: if later launches silently fail, absmax ~= 50000
  diag_write<<<16, 256, 0, stream>>>(out, 50000.f);

  if (ws_size < WS_NEED){
    diag_write<<<16, 256, 0, stream>>>(out, 100000.f + (float)(ws_size >> 20));
    return;
  }

  char* ws = (char*)d_ws;
  unsigned short* Xcat = (unsigned short*)(ws + OFF_XCAT);
  unsigned short* Wcat = (unsigned short*)(ws + OFF_WCAT);
  float* bias_cat      = (float*)(ws + OFF_BIAS);
  unsigned int* hw     = (unsigned int*)(ws + OFF_HW);
  unsigned int* ctr    = (unsigned int*)(ws + OFF_CTR);

  // zero tagged-word h buffer + counters every call (tags restart; h_0 = 0 with tag 0)
  hipMemsetAsync(ws + OFF_HW, 0, 524288 + 1024, stream);

  prep_w<<<8192, 256, 0, stream>>>(Wii, Wif, Wig, Wio, Whi, Whf, Whg, Who,
                                   Bii, Bif, Big, Bio, Bhi, Bhf, Bhg, Bho,
                                   Wcat, bias_cat);

  stageA_fused<<<8192, 256, 0, stream>>>(x_num, x_state, emb,
                                         num_w0, num_b0, num_w1, num_b1,
                                         st_w0, st_b0, st_w1, st_b1, Xcat);

  hipFuncSetAttribute((const void*)lstm_pk,
                      hipFuncAttributeMaxDynamicSharedMemorySize, 65536);
  lstm_pk<<<256, 256, 65536, stream>>>(Xcat, Wcat, bias_cat, hw, ctr);

  out_gemm<<<128, 256, 0, stream>>>(hw, ctr, out_w, out_b, out);
}

// Round 16
// 4992.970 us; speedup vs baseline: 2.8356x; 1.0713x over previous
//
#include <hip/hip_runtime.h>
#include <hip/hip_bf16.h>

typedef __attribute__((ext_vector_type(4))) float f4;
typedef __attribute__((ext_vector_type(4))) float f32x4;
typedef __attribute__((ext_vector_type(8))) short bf16x8;
typedef __attribute__((ext_vector_type(4))) unsigned u32x4;
typedef unsigned long long ull;

// ---------------- workspace layout (bytes) ----------------
#define OFF_XCAT   0ull                 // ushort [1024][128][512]  time-major LSTM input
#define OFF_WCAT   134217728ull         // ushort [2048][1024]      packed LSTM weights
#define OFF_BIAS   138412032ull         // float  [2048]
#define OFF_HW     138420224ull         // uint   [2][8][16][512]   tagged h words: (h_bf16<<16)|step_tag
#define OFF_CTR    138944512ull         // uint   [256]             counters/diag
#define OFF_WT     138945536ull         // float  [163840]          transposed stage-A weights
#define WS_NEED    139600896ull

__device__ inline unsigned short f2bf(float x){
  unsigned u = __float_as_uint(x);
  unsigned r = (u + 0x7FFFu + ((u >> 16) & 1u)) >> 16;   // RNE
  return (unsigned short)r;
}
__device__ inline float bf2f(unsigned short s){ return __uint_as_float(((unsigned)s) << 16); }

// ---------------- diagnostic fill (absmax is the debug channel) ----------------
__global__ void __launch_bounds__(256) diag_write(float* out, float val){
  out[blockIdx.x * 256 + threadIdx.x] = val;
}

// ---------------- LSTM weight repack ----------------
__global__ void __launch_bounds__(256) prep_w(
    const float* Wii, const float* Wif, const float* Wig, const float* Wio,
    const float* Whi, const float* Whf, const float* Whg, const float* Who,
    const float* Bii, const float* Bif, const float* Big, const float* Bio,
    const float* Bhi, const float* Bhf, const float* Bhg, const float* Bho,
    unsigned short* Wcat, float* bias_cat){
  int e = blockIdx.x * 256 + threadIdx.x;        // < 2048*1024
  int col = e >> 10, k = e & 1023;
  int u = col >> 2, g = col & 3;
  float v;
  if (k < 512){
    const float* p = (g==0)?Wii:((g==1)?Wif:((g==2)?Wig:Wio));
    v = p[u*512 + k];
  } else {
    const float* p = (g==0)?Whi:((g==1)?Whf:((g==2)?Whg:Who));
    v = p[u*512 + (k-512)];
  }
  Wcat[e] = f2bf(v);
  if (e < 2048){
    int u2 = e >> 2, g2 = e & 3;
    const float* bx = (g2==0)?Bii:((g2==1)?Bif:((g2==2)?Big:Bio));
    const float* bh = (g2==0)?Bhi:((g2==1)?Bhf:((g2==2)?Bhg:Bho));
    bias_cat[e] = bx[u2] + bh[u2];
  }
}

// ---------------- stage-A weight transpose: W0T[64][256], W1T[256][256] per branch ----------------
__global__ void __launch_bounds__(256) prep_wt(
    const float* __restrict__ num_w0, const float* __restrict__ num_w1,
    const float* __restrict__ st_w0,  const float* __restrict__ st_w1,
    float* __restrict__ wt){
  int e = blockIdx.x * 256 + threadIdx.x;        // < 163840
  int br = e >= 81920;
  int e2 = e - br*81920;
  const float* W0 = br ? st_w0 : num_w0;
  const float* W1 = br ? st_w1 : num_w1;
  float* base = wt + br*81920;
  if (e2 < 16384){
    int k = e2 >> 8, c = e2 & 255;
    base[k*256 + c] = W0[c*64 + k];
  } else {
    int e3 = e2 - 16384;
    int k = e3 >> 8, c = e3 & 255;
    base[16384 + k*256 + c] = W1[c*256 + k];
  }
}

// ---------------- fused stage A v2: direct coalesced L2 weight reads, 20.5KB LDS ----------------
// Bit-identical K-accumulation order to the r11 version (ascending k in steps of 4).
__global__ void __launch_bounds__(256) stageA_fused(
    const float* __restrict__ xnum, const int* __restrict__ xstate,
    const float* __restrict__ emb,
    const float* __restrict__ wt,           // transposed weights (both branches)
    const float* __restrict__ num_b0, const float* __restrict__ num_b1,
    const float* __restrict__ st_b0,  const float* __restrict__ st_b1,
    unsigned short* __restrict__ Xcat){
  __shared__ float xb[16*68];
  __shared__ float h1[16*260];
  int tid = threadIdx.x;
  long tok0 = (long)blockIdx.x * 16;
  int tg = tid >> 6, c4 = tid & 63;

  #pragma unroll 1
  for (int br = 0; br < 2; ++br){
    const float* W0T = wt + br*81920;          // [64][256]
    const float* W1T = W0T + 16384;            // [256][256]
    const float* b0 = br ? st_b0 : num_b0;
    const float* b1 = br ? st_b1 : num_b1;

    __syncthreads();   // protect xb/h1 from previous branch reads
    if (br == 0){
      int tk = tid >> 4, q = tid & 15;
      f4 v = *(const f4*)(xnum + (tok0+tk)*64 + q*4);
      float* d = xb + tk*68 + q*4;
      d[0]=v.x; d[1]=v.y; d[2]=v.z; d[3]=v.w;
    } else {
      int tk = tid >> 4, j = tid & 15;
      int idx = xstate[(tok0+tk)*16 + j];
      f4 v = *(const f4*)(emb + idx*4);
      float* d = xb + tk*68 + j*4;
      d[0]=v.x; d[1]=v.y; d[2]=v.z; d[3]=v.w;
    }
    __syncthreads();

    // ---- layer 1: K=64, weights direct from L2 (coalesced rows of W0T) ----
    float acc[4][4];
    { f4 bv = *(const f4*)(b0 + c4*4);
      #pragma unroll
      for (int j=0;j<4;j++){ acc[j][0]=bv.x; acc[j][1]=bv.y; acc[j][2]=bv.z; acc[j][3]=bv.w; } }
    #pragma unroll 4
    for (int kq=0; kq<16; kq++){
      int k0 = kq*4;
      f4 a0 = *(const f4*)(xb + (tg*4+0)*68 + k0);
      f4 a1 = *(const f4*)(xb + (tg*4+1)*68 + k0);
      f4 a2 = *(const f4*)(xb + (tg*4+2)*68 + k0);
      f4 a3 = *(const f4*)(xb + (tg*4+3)*68 + k0);
      f4 w0 = *(const f4*)(W0T + (k0+0)*256 + c4*4);
      f4 w1 = *(const f4*)(W0T + (k0+1)*256 + c4*4);
      f4 w2 = *(const f4*)(W0T + (k0+2)*256 + c4*4);
      f4 w3 = *(const f4*)(W0T + (k0+3)*256 + c4*4);
      #pragma unroll
      for (int j=0;j<4;j++){
        f4 a = (j==0)?a0:((j==1)?a1:((j==2)?a2:a3));
        #pragma unroll
        for (int d=0; d<4; d++)
          acc[j][d] += a.x*w0[d] + a.y*w1[d] + a.z*w2[d] + a.w*w3[d];
      }
    }
    #pragma unroll
    for (int j=0;j<4;j++){
      float v0=fmaxf(acc[j][0],0.f), v1=fmaxf(acc[j][1],0.f);
      float v2=fmaxf(acc[j][2],0.f), v3=fmaxf(acc[j][3],0.f);
      float s1 = v0+v1+v2+v3, s2 = v0*v0+v1*v1+v2*v2+v3*v3;
      for (int off=1; off<64; off<<=1){ s1 += __shfl_xor(s1, off); s2 += __shfl_xor(s2, off); }
      float mu = s1 * (1.f/256.f);
      float rs = rsqrtf(s2*(1.f/256.f) - mu*mu + 1e-5f);
      f4 o; o.x=(v0-mu)*rs; o.y=(v1-mu)*rs; o.z=(v2-mu)*rs; o.w=(v3-mu)*rs;
      *(f4*)(h1 + (tg*4+j)*260 + c4*4) = o;
    }
    __syncthreads();

    // ---- layer 2: K=256, weights direct from L2 (coalesced rows of W1T) ----
    float ac2[4][4];
    { f4 bv = *(const f4*)(b1 + c4*4);
      #pragma unroll
      for (int j=0;j<4;j++){ ac2[j][0]=bv.x; ac2[j][1]=bv.y; ac2[j][2]=bv.z; ac2[j][3]=bv.w; } }
    #pragma unroll 4
    for (int kq=0; kq<64; kq++){
      int k0 = kq*4;
      f4 a0 = *(const f4*)(h1 + (tg*4+0)*260 + k0);
      f4 a1 = *(const f4*)(h1 + (tg*4+1)*260 + k0);
      f4 a2 = *(const f4*)(h1 + (tg*4+2)*260 + k0);
      f4 a3 = *(const f4*)(h1 + (tg*4+3)*260 + k0);
      f4 w0 = *(const f4*)(W1T + (k0+0)*256 + c4*4);
      f4 w1 = *(const f4*)(W1T + (k0+1)*256 + c4*4);
      f4 w2 = *(const f4*)(W1T + (k0+2)*256 + c4*4);
      f4 w3 = *(const f4*)(W1T + (k0+3)*256 + c4*4);
      #pragma unroll
      for (int j=0;j<4;j++){
        f4 a = (j==0)?a0:((j==1)?a1:((j==2)?a2:a3));
        #pragma unroll
        for (int d=0; d<4; d++)
          ac2[j][d] += a.x*w0[d] + a.y*w1[d] + a.z*w2[d] + a.w*w3[d];
      }
    }
    #pragma unroll
    for (int j=0;j<4;j++){
      float v0=fmaxf(ac2[j][0],0.f), v1=fmaxf(ac2[j][1],0.f);
      float v2=fmaxf(ac2[j][2],0.f), v3=fmaxf(ac2[j][3],0.f);
      float s1 = v0+v1+v2+v3, s2 = v0*v0+v1*v1+v2*v2+v3*v3;
      for (int off=1; off<64; off<<=1){ s1 += __shfl_xor(s1, off); s2 += __shfl_xor(s2, off); }
      float mu = s1 * (1.f/256.f);
      float rs = rsqrtf(s2*(1.f/256.f) - mu*mu + 1e-5f);
      long tok = tok0 + tg*4 + j;
      long bb = tok >> 10, ss = tok & 1023;
      unsigned short* o = Xcat + (ss*128 + bb)*512 + br*256 + c4*4;
      unsigned lo = (unsigned)f2bf((v0-mu)*rs) | ((unsigned)f2bf((v1-mu)*rs) << 16);
      unsigned hi = (unsigned)f2bf((v2-mu)*rs) | ((unsigned)f2bf((v3-mu)*rs) << 16);
      ((unsigned*)o)[0] = lo; ((unsigned*)o)[1] = hi;
    }
  }
}

// ---------------- coalesced agent-scope poll load: 8 x dwordx4, sc1 ----------------
__device__ __forceinline__ void ld8x16_sc1(const unsigned* p, u32x4* v){
  asm volatile(
    "global_load_dwordx4 %0, %8, off sc1\n\t"
    "global_load_dwordx4 %1, %8, off offset:256 sc1\n\t"
    "global_load_dwordx4 %2, %8, off offset:512 sc1\n\t"
    "global_load_dwordx4 %3, %8, off offset:768 sc1\n\t"
    "global_load_dwordx4 %4, %8, off offset:1024 sc1\n\t"
    "global_load_dwordx4 %5, %8, off offset:1280 sc1\n\t"
    "global_load_dwordx4 %6, %8, off offset:1536 sc1\n\t"
    "global_load_dwordx4 %7, %8, off offset:1792 sc1\n\t"
    "s_waitcnt vmcnt(0)"
    : "=&v"(v[0]),"=&v"(v[1]),"=&v"(v[2]),"=&v"(v[3]),
      "=&v"(v[4]),"=&v"(v[5]),"=&v"(v[6]),"=&v"(v[7])
    : "v"(p) : "memory");
}

// ---------------- persistent LSTM kernel (r11 verbatim — best-measured variant) ----------------
__global__ void __launch_bounds__(256, 1) lstm_pk(
    const unsigned short* __restrict__ Xcat,
    const unsigned short* __restrict__ Wcat,
    const float* __restrict__ bias_cat,
    unsigned int* __restrict__ hw,
    unsigned int* __restrict__ ctr){
  __shared__ __align__(16) char actb[32768];   // h act tiles, double buffer
  __shared__ int okf, sdead;
  int tid = threadIdx.x;
  int lane = tid & 63, w = tid >> 6;
  int g = blockIdx.x & 7, m = blockIdx.x >> 3;

  int colg = 64*m + 16*w + (lane & 15);
  bf16x8 wf[32];
  {
    const bf16x8* wsrc = (const bf16x8*)(Wcat + (long)colg*1024 + (lane>>4)*8);
    #pragma unroll
    for (int s=0;s<32;s++) wf[s] = wsrc[s*4];
  }
  int cb = 64*m + 16*w + 4*(lane>>4);
  f32x4 bias4;
  bias4.x = bias_cat[cb+0]; bias4.y = bias_cat[cb+1];
  bias4.z = bias_cat[cb+2]; bias4.w = bias_cat[cb+3];

  if (tid == 0){
    __hip_atomic_fetch_add(&ctr[255], 1u, __ATOMIC_RELAXED, __HIP_MEMORY_SCOPE_AGENT);
    unsigned v = 0; int it = 0;
    do {
      v = __hip_atomic_load(&ctr[255], __ATOMIC_RELAXED, __HIP_MEMORY_SCOPE_AGENT);
      if (v >= 256u) break;
      __builtin_amdgcn_s_sleep(8);
    } while (++it < 2000000);
    okf = (v >= 256u) ? 1 : 0;
    sdead = 0;
  }
  __syncthreads();
  if (!okf) return;

  float cst = 0.f;
  int r16 = tid >> 4, q16 = tid & 15;

  f32x4 acc0, acc1;
  {
    bf16x8 xf[16];
    const bf16x8* xsrc = (const bf16x8*)(Xcat + ((long)0*128 + g*16 + (lane&15))*512 + (lane>>4)*8);
    #pragma unroll
    for (int s=0;s<16;s++) xf[s] = xsrc[s*4];
    acc0 = bias4;
    acc1.x=0.f; acc1.y=0.f; acc1.z=0.f; acc1.w=0.f;
    #pragma unroll
    for (int s=0;s<16;s+=2){
      acc0 = __builtin_amdgcn_mfma_f32_16x16x32_bf16(wf[s],   xf[s],   acc0, 0, 0, 0);
      acc1 = __builtin_amdgcn_mfma_f32_16x16x32_bf16(wf[s+1], xf[s+1], acc1, 0, 0, 0);
    }
  }

  #pragma unroll 1
  for (int t=0; t<1024; ++t){
    if (t == 0){
      char* hl = actb;                      // h_0 = 0
      #pragma unroll
      for (int i=0;i<8;i++){
        int byt = (r16*1024 + q16*8 + i*128) ^ ((r16 & 7) << 4);
        *(ull*)(hl + byt) = 0ull;
      }
    } else {
      const unsigned* hp = hw + ((long)(t&1)*65536) + g*8192 + r16*512 + q16*4;
      u32x4 hv[8];
      unsigned tt = (unsigned)t; int itc = 0;
      for (;;){
        ld8x16_sc1(hp, hv);
        unsigned bad = 0;
        #pragma unroll
        for (int i=0;i<8;i++){
          bad |= (hv[i].x & 0xFFFFu) ^ tt;
          bad |= (hv[i].y & 0xFFFFu) ^ tt;
          bad |= (hv[i].z & 0xFFFFu) ^ tt;
          bad |= (hv[i].w & 0xFFFFu) ^ tt;
        }
        if (!bad) break;
        if ((itc & 31) == 31 && *(volatile int*)&sdead) break;
        if (++itc > 200000){
          *(volatile int*)&sdead = 1;
          __hip_atomic_store(&ctr[252], tt, __ATOMIC_RELAXED, __HIP_MEMORY_SCOPE_AGENT);
          break;
        }
      }
      char* hl = actb + (t&1)*16384;
      #pragma unroll
      for (int i=0;i<8;i++){
        unsigned p0 = (hv[i].x >> 16) | (hv[i].y & 0xFFFF0000u);
        unsigned p1 = (hv[i].z >> 16) | (hv[i].w & 0xFFFF0000u);
        ull pp = (ull)p0 | ((ull)p1 << 32);
        int byt = (r16*1024 + q16*8 + i*128) ^ ((r16 & 7) << 4);
        *(ull*)(hl + byt) = pp;
      }
    }
    __syncthreads();
    if (*(volatile int*)&sdead) break;
    {
      const char* hl = actb + (t&1)*16384;
      #pragma unroll
      for (int s=0;s<16;s+=2){
        int by0 = ((lane&15)*1024 + s*64     + (lane>>4)*16) ^ (((lane&15)&7) << 4);
        int by1 = ((lane&15)*1024 + (s+1)*64 + (lane>>4)*16) ^ (((lane&15)&7) << 4);
        bf16x8 b0 = *(const bf16x8*)(hl + by0);
        bf16x8 b1 = *(const bf16x8*)(hl + by1);
        acc0 = __builtin_amdgcn_mfma_f32_16x16x32_bf16(wf[16+s], b0, acc0, 0, 0, 0);
        acc1 = __builtin_amdgcn_mfma_f32_16x16x32_bf16(wf[17+s], b1, acc1, 0, 0, 0);
      }
    }
    float gi = acc0.x + acc1.x, gf = acc0.y + acc1.y;
    float gg = acc0.z + acc1.z, go = acc0.w + acc1.w;
    float iv = 1.f / (1.f + __expf(-gi));
    float fv = 1.f / (1.f + __expf(-gf));
    float e2 = __expf(-2.f * gg);
    float gv = (1.f - e2) / (1.f + e2);
    float ov = 1.f / (1.f + __expf(-go));
    cst = fv * cst + iv * gv;
    float e2c = __expf(-2.f * cst);
    float hout = ov * (1.f - e2c) / (1.f + e2c);
    {
      unsigned short hb16 = f2bf(hout);
      int unit = 16*m + 4*w + (lane >> 4);
      int row  = lane & 15;
      unsigned word = ((unsigned)hb16 << 16) | (unsigned)((t+1) & 0xFFFF);
      unsigned int* dst = hw + ((long)((t+1)&1)*65536) + g*8192 + row*512 + unit;
      __hip_atomic_store(dst, word, __ATOMIC_RELAXED, __HIP_MEMORY_SCOPE_AGENT);
    }
    {
      int tn = (t < 1023) ? (t+1) : 1023;
      bf16x8 xf[16];
      const bf16x8* xsrc = (const bf16x8*)(Xcat + ((long)tn*128 + g*16 + (lane&15))*512 + (lane>>4)*8);
      #pragma unroll
      for (int s=0;s<16;s++) xf[s] = xsrc[s*4];
      acc0 = bias4;
      acc1.x=0.f; acc1.y=0.f; acc1.z=0.f; acc1.w=0.f;
      #pragma unroll
      for (int s=0;s<16;s+=2){
        acc0 = __builtin_amdgcn_mfma_f32_16x16x32_bf16(wf[s],   xf[s],   acc0, 0, 0, 0);
        acc1 = __builtin_amdgcn_mfma_f32_16x16x32_bf16(wf[s+1], xf[s+1], acc1, 0, 0, 0);
      }
    }
  }

  __syncthreads();
  if (tid == 0 && !sdead)
    __hip_atomic_fetch_add(&ctr[251], 1u, __ATOMIC_RELAXED, __HIP_MEMORY_SCOPE_AGENT);
}

// ---------------- output projection (reads tagged words, parity 0) ----------------
__global__ void __launch_bounds__(256) out_gemm(
    const unsigned int* __restrict__ hw, const unsigned int* __restrict__ ctr,
    const float* __restrict__ out_w, const float* __restrict__ out_b,
    float* __restrict__ out){
  unsigned done = ctr[251], arriv = ctr[255], dead = ctr[252];
  if (dead != 0u || done != 256u){
    float v = dead ? (20000.f + (float)dead) : (10000.f + (float)arriv);
    if (threadIdx.x < 32) out[blockIdx.x*32 + threadIdx.x] = v;
    return;
  }
  __shared__ float part[8][32];
  int b = blockIdx.x;
  int g = b >> 4, r = b & 15;
  const unsigned int* hrow = hw + (long)g*8192 + r*512;   // parity 0 holds h after step 1024
  int col = threadIdx.x & 31, p = threadIdx.x >> 5;
  float s = 0.f;
  for (int u = p*64; u < p*64 + 64; ++u)
    s += bf2f((unsigned short)(hrow[u] >> 16)) * out_w[col*512 + u];
  part[p][col] = s;
  __syncthreads();
  if (p == 0){
    float t = out_b[col];
    #pragma unroll
    for (int i=0;i<8;i++) t += part[i][col];
    out[b*32 + col] = t;
  }
}

extern "C" void kernel_launch(void* const* d_in, const int* in_sizes, int n_in,
                              void* d_out, int out_size, void* d_ws, size_t ws_size,
                              hipStream_t stream){
  const float* x_num   = (const float*)d_in[0];
  const int*   x_state = (const int*)d_in[1];
  const float* num_w0  = (const float*)d_in[2];
  const float* num_b0  = (const float*)d_in[3];
  const float* num_w1  = (const float*)d_in[4];
  const float* num_b1  = (const float*)d_in[5];
  const float* emb     = (const float*)d_in[6];
  const float* st_w0   = (const float*)d_in[7];
  const float* st_b0   = (const float*)d_in[8];
  const float* st_w1   = (const float*)d_in[9];
  const float* st_b1   = (const float*)d_in[10];
  const float* Wii = (const float*)d_in[11];
  const float* Whi = (const float*)d_in[12];
  const float* Wif = (const float*)d_in[13];
  const float* Whf = (const float*)d_in[14];
  const float* Wig = (const float*)d_in[15];
  const float* Whg = (const float*)d_in[16];
  const float* Wio = (const float*)d_in[17];
  const float* Who = (const float*)d_in[18];
  const float* Bii = (const float*)d_in[19];
  const float* Bhi = (const float*)d_in[20];
  const float* Bif = (const float*)d_in[21];
  const float* Bhf = (const float*)d_in[22];
  const float* Big = (const float*)d_in[23];
  const float* Bhg = (const float*)d_in[24];
  const float* Bio = (const float*)d_in[25];
  const float* Bho = (const float*)d_in[26];
  const float* out_w = (const float*)d_in[27];
  const float* out_b = (const float*)d_in[28];

  float* out = (float*)d_out;

  // sentinel: if later launches silently fail, absmax ~= 50000
  diag_write<<<16, 256, 0, stream>>>(out, 50000.f);

  if (ws_size < WS_NEED){
    diag_write<<<16, 256, 0, stream>>>(out, 100000.f + (float)(ws_size >> 20));
    return;
  }

  char* ws = (char*)d_ws;
  unsigned short* Xcat = (unsigned short*)(ws + OFF_XCAT);
  unsigned short* Wcat = (unsigned short*)(ws + OFF_WCAT);
  float* bias_cat      = (float*)(ws + OFF_BIAS);
  unsigned int* hw     = (unsigned int*)(ws + OFF_HW);
  unsigned int* ctr    = (unsigned int*)(ws + OFF_CTR);
  float* wt            = (float*)(ws + OFF_WT);

  // zero tagged-word h buffer + counters every call (tags restart; h_0 = 0 with tag 0)
  hipMemsetAsync(ws + OFF_HW, 0, 524288 + 1024, stream);

  prep_w<<<8192, 256, 0, stream>>>(Wii, Wif, Wig, Wio, Whi, Whf, Whg, Who,
                                   Bii, Bif, Big, Bio, Bhi, Bhf, Bhg, Bho,
                                   Wcat, bias_cat);

  prep_wt<<<640, 256, 0, stream>>>(num_w0, num_w1, st_w0, st_w1, wt);

  stageA_fused<<<8192, 256, 0, stream>>>(x_num, x_state, emb, wt,
                                         num_b0, num_b1, st_b0, st_b1, Xcat);

  lstm_pk<<<256, 256, 0, stream>>>(Xcat, Wcat, bias_cat, hw, ctr);

  out_gemm<<<128, 256, 0, stream>>>(hw, ctr, out_w, out_b, out);
}